// Round 8
// baseline (201.703 us; speedup 1.0000x reference)
//
#include <hip/hip_runtime.h>
#include <hip/hip_bf16.h>
#include <math.h>

// Problem constants (B=2, L=1024, d_model=512, d_inner=1024, H=8, N=16, hd=128,
// dt_rank=32, out_dim=560). T = B*L = 2048 tokens.
//
// Pipeline (GEMMs in bf16 MFMA, scan math f32):
//  0) cvt_all: x,W_in,W_x,W_out -> bf16 + W_dt transpose (one kernel)
//  1) gemm_bf16_128: xz[T,2048] = x_bf @ Win_bf^T        (f32 out)
//  2) conv_silu: dx[t,c].y = silu(dwconv(xz[:,:1024])), xc_bf (bf16 copy),
//     AND in-place silu on the z-half: xz[t,1024+c] = silu(xz[t,1024+c])
//  3) gemm_bf16_64: proj[T,560] = xc_bf @ Wx_bf^T
//  4) pack2: dx[t,c].x = softplus(proj[:, :32] . W_dtT + b_dt);
//            scanin[t,h,n]={Br,Bi,Cr,Ci}; gates[t,h]={1-lg, lg*eg}
//  5) chunked complex scan (part1/part2/part3); part3 writes yg_bf (bf16)
//     part1/part3: COPY-FREE modulo-4 pipeline, loads lead consumption by
//     2 substeps (~2 step-bodies) -> covers L2 latency.  No rotation movs.
//  6) gemm_bf16_64: out[T,512] = yg_bf @ Wout_bf^T

typedef __attribute__((ext_vector_type(8))) short bf16x8;
typedef __attribute__((ext_vector_type(4))) float f32x4;

__device__ __forceinline__ float fexp2(float x) {
  float r; asm("v_exp_f32 %0, %1" : "=v"(r) : "v"(x)); return r;
}
__device__ __forceinline__ float fsin_rev(float x) {
  float r; asm("v_sin_f32 %0, %1" : "=v"(r) : "v"(x)); return r;
}
__device__ __forceinline__ float fcos_rev(float x) {
  float r; asm("v_cos_f32 %0, %1" : "=v"(r) : "v"(x)); return r;
}
__device__ __forceinline__ short f2bf(float f) {  // round-to-nearest-even
  unsigned u = __float_as_uint(f);
  return (short)((u + 0x7FFFu + ((u >> 16) & 1u)) >> 16);
}

// sum across the 16-lane row (n = lane&15) via DPP rotations; all lanes get
// the total.  row_ror:k = dpp_ctrl 0x120|k; rows of 16 align with n-groups.
#define ROR_ADD(y, CTRL)                                                     \
  {                                                                          \
    int _r = __builtin_amdgcn_update_dpp(0, __float_as_int(y), CTRL, 0xF,    \
                                         0xF, false);                        \
    y += __int_as_float(_r);                                                 \
  }

// ---------------------------------------------------------------------------
// Fused f32->bf16 conversion of x, W_in, W_x, W_out (float4 granules) plus
// W_dt transpose.  Segments: 262144 | 262144 | 143360 | 131072 f4 granules,
// then 32768 scalar transpose elems.  Grid 3248*256 = 831488 = exact.
// ---------------------------------------------------------------------------
__global__ __launch_bounds__(256)
void cvt_all_k(const float* __restrict__ x, const float* __restrict__ W_in,
               const float* __restrict__ W_x, const float* __restrict__ W_out,
               const float* __restrict__ W_dt,
               short* __restrict__ x_bf, short* __restrict__ win_bf,
               short* __restrict__ wx_bf, short* __restrict__ wout_bf,
               float* __restrict__ W_dtT) {
  const int i = blockIdx.x * 256 + threadIdx.x;
  if (i < 798720) {
    const float4* src; short4* dst; int off;
    if (i < 262144)      { src = (const float4*)x;     dst = (short4*)x_bf;    off = i; }
    else if (i < 524288) { src = (const float4*)W_in;  dst = (short4*)win_bf;  off = i - 262144; }
    else if (i < 667648) { src = (const float4*)W_x;   dst = (short4*)wx_bf;   off = i - 524288; }
    else                 { src = (const float4*)W_out; dst = (short4*)wout_bf; off = i - 667648; }
    const float4 v = src[off];
    short4 o;
    o.x = f2bf(v.x); o.y = f2bf(v.y); o.z = f2bf(v.z); o.w = f2bf(v.w);
    dst[off] = o;
  } else {
    const int j = i - 798720;  // 0..32767: W_dtT[r*1024+c] = W_dt[c*32+r]
    W_dtT[j] = W_dt[(j & 1023) * 32 + (j >> 10)];
  }
}

// ---------------------------------------------------------------------------
// bf16 MFMA GEMM (NT), 128x128 tile / 256 threads (4 waves x 64x64 quadrant).
// BK=32, LDS +8-short pad (row stride 80 B -> 2-way bank alias, free).
// ---------------------------------------------------------------------------
__global__ __launch_bounds__(256)
void gemm_bf16_128(const short* __restrict__ A, const short* __restrict__ W,
                   float* __restrict__ C, int N, int K) {
  __shared__ short As[128][40];
  __shared__ short Ws[128][40];
  const int tid  = threadIdx.x;
  const int m0   = blockIdx.y * 128;
  const int n0   = blockIdx.x * 128;
  const int lane = tid & 63;
  const int wid  = tid >> 6;
  const int wm   = (wid >> 1) * 64;
  const int wn   = (wid & 1) * 64;
  const int r0   = tid >> 2;
  const int q    = (tid & 3) * 8;
  const int lrow = lane & 15;
  const int lk   = (lane >> 4) * 8;

  f32x4 acc[4][4] = {};

  for (int k0 = 0; k0 < K; k0 += 32) {
    const size_t abase = (size_t)(m0 + r0) * K + k0 + q;
    const uint4 a0v = *reinterpret_cast<const uint4*>(A + abase);
    const uint4 a1v = *reinterpret_cast<const uint4*>(A + abase + (size_t)64 * K);
    const int wr0 = n0 + r0, wr1 = wr0 + 64;
    uint4 w0v = make_uint4(0, 0, 0, 0), w1v = make_uint4(0, 0, 0, 0);
    if (wr0 < N) w0v = *reinterpret_cast<const uint4*>(W + (size_t)wr0 * K + k0 + q);
    if (wr1 < N) w1v = *reinterpret_cast<const uint4*>(W + (size_t)wr1 * K + k0 + q);

    __syncthreads();
    *reinterpret_cast<uint4*>(&As[r0][q])      = a0v;
    *reinterpret_cast<uint4*>(&As[r0 + 64][q]) = a1v;
    *reinterpret_cast<uint4*>(&Ws[r0][q])      = w0v;
    *reinterpret_cast<uint4*>(&Ws[r0 + 64][q]) = w1v;
    __syncthreads();

    bf16x8 af[4], bfr[4];
#pragma unroll
    for (int i = 0; i < 4; ++i)
      af[i] = *reinterpret_cast<const bf16x8*>(&As[wm + i * 16 + lrow][lk]);
#pragma unroll
    for (int j = 0; j < 4; ++j)
      bfr[j] = *reinterpret_cast<const bf16x8*>(&Ws[wn + j * 16 + lrow][lk]);
#pragma unroll
    for (int i = 0; i < 4; ++i)
#pragma unroll
      for (int j = 0; j < 4; ++j)
        acc[i][j] = __builtin_amdgcn_mfma_f32_16x16x32_bf16(af[i], bfr[j],
                                                            acc[i][j], 0, 0, 0);
  }

  const int crow = (lane >> 4) * 4;
  const int ccol = lane & 15;
#pragma unroll
  for (int i = 0; i < 4; ++i) {
#pragma unroll
    for (int j = 0; j < 4; ++j) {
      const int col = n0 + wn + j * 16 + ccol;
      if (col < N) {
        const int row = m0 + wm + i * 16 + crow;
#pragma unroll
        for (int r = 0; r < 4; ++r)
          C[(size_t)(row + r) * N + col] = acc[i][j][r];
      }
    }
  }
}

// ---------------------------------------------------------------------------
// bf16 MFMA GEMM (NT), 64x64 tile / 256 threads (4 waves x 32x32 quadrant).
// ---------------------------------------------------------------------------
__global__ __launch_bounds__(256)
void gemm_bf16_64(const short* __restrict__ A, const short* __restrict__ W,
                  float* __restrict__ C, int N, int K) {
  __shared__ short As[64][40];
  __shared__ short Ws[64][40];
  const int tid  = threadIdx.x;
  const int m0   = blockIdx.y * 64;
  const int n0   = blockIdx.x * 64;
  const int lane = tid & 63;
  const int wid  = tid >> 6;
  const int wm   = (wid >> 1) * 32;
  const int wn   = (wid & 1) * 32;
  const int r0   = tid >> 2;
  const int q    = (tid & 3) * 8;
  const int lrow = lane & 15;
  const int lk   = (lane >> 4) * 8;

  f32x4 acc[2][2] = {};

  for (int k0 = 0; k0 < K; k0 += 32) {
    const uint4 a0v =
        *reinterpret_cast<const uint4*>(A + (size_t)(m0 + r0) * K + k0 + q);
    const int wr0 = n0 + r0;
    uint4 w0v = make_uint4(0, 0, 0, 0);
    if (wr0 < N) w0v = *reinterpret_cast<const uint4*>(W + (size_t)wr0 * K + k0 + q);

    __syncthreads();
    *reinterpret_cast<uint4*>(&As[r0][q]) = a0v;
    *reinterpret_cast<uint4*>(&Ws[r0][q]) = w0v;
    __syncthreads();

    bf16x8 af[2], bfr[2];
#pragma unroll
    for (int i = 0; i < 2; ++i)
      af[i] = *reinterpret_cast<const bf16x8*>(&As[wm + i * 16 + lrow][lk]);
#pragma unroll
    for (int j = 0; j < 2; ++j)
      bfr[j] = *reinterpret_cast<const bf16x8*>(&Ws[wn + j * 16 + lrow][lk]);
#pragma unroll
    for (int i = 0; i < 2; ++i)
#pragma unroll
      for (int j = 0; j < 2; ++j)
        acc[i][j] = __builtin_amdgcn_mfma_f32_16x16x32_bf16(af[i], bfr[j],
                                                            acc[i][j], 0, 0, 0);
  }

  const int crow = (lane >> 4) * 4;
  const int ccol = lane & 15;
#pragma unroll
  for (int i = 0; i < 2; ++i) {
#pragma unroll
    for (int j = 0; j < 2; ++j) {
      const int col = n0 + wn + j * 16 + ccol;
      if (col < N) {
        const int row = m0 + wm + i * 16 + crow;
#pragma unroll
        for (int r = 0; r < 4; ++r)
          C[(size_t)(row + r) * N + col] = acc[i][j][r];
      }
    }
  }
}

// ---------------------------------------------------------------------------
// Causal depthwise conv (K=3) + silu; writes dx.y (f32) and xc_bf (bf16).
// Also applies silu IN-PLACE to the z half: xz[t,1024+c] = silu(...).
// ---------------------------------------------------------------------------
__global__ __launch_bounds__(256)
void conv_silu_k(float* __restrict__ xz, const float* __restrict__ conv_w,
                 const float* __restrict__ conv_b, float* __restrict__ dxf,
                 short* __restrict__ xcb) {
  const int idx = blockIdx.x * 256 + threadIdx.x;
  const int c = idx & 1023;
  const int t = idx >> 10;
  const int l = t & 1023;
  const float* xp = xz + (size_t)t * 2048 + c;
  float acc = conv_b[c];
  const float w0 = conv_w[c * 3 + 0];
  const float w1 = conv_w[c * 3 + 1];
  const float w2 = conv_w[c * 3 + 2];
  acc += w2 * xp[0];
  if (l >= 1) acc += w1 * xp[-2048];
  if (l >= 2) acc += w0 * xp[-2 * 2048];
  const float v = acc / (1.f + __expf(-acc));
  dxf[2 * (size_t)idx + 1] = v;
  xcb[idx] = f2bf(v);
  // in-place silu on z
  float* zp = xz + (size_t)t * 2048 + 1024 + c;
  const float zv = *zp;
  *zp = zv / (1.f + __expf(-zv));
}

// ---------------------------------------------------------------------------
// pack2: fused delta + scanin-pack + gates.
// ---------------------------------------------------------------------------
__global__ __launch_bounds__(256)
void pack2_k(const float* __restrict__ proj, const float* __restrict__ W_dtT,
             const float* __restrict__ b_dt, float* __restrict__ dxf,
             float4* __restrict__ scanin, float2* __restrict__ gates) {
  const int idx = blockIdx.x * 256 + threadIdx.x;  // 2097152 + 262144
  if (idx < 2097152) {
    const int c = idx & 1023;
    const int t = idx >> 10;
    const float* pr = proj + (size_t)t * 560;
    float acc = b_dt[c];
#pragma unroll
    for (int r = 0; r < 32; ++r) acc = fmaf(pr[r], W_dtT[r * 1024 + c], acc);
    dxf[2 * (size_t)idx] = fmaxf(acc, 0.f) + log1pf(__expf(-fabsf(acc)));
  } else {
    const int j = idx - 2097152;
    const int n = j & 15;
    const int h = (j >> 4) & 7;
    const int t = j >> 7;
    const float* pr = proj + (size_t)t * 560;
    const int hn = h * 16 + n;
    scanin[j] = make_float4(pr[32 + hn], pr[160 + hn], pr[288 + hn], pr[416 + hn]);
    if (n == 0) {
      const float lg = 1.f / (1.f + __expf(-pr[544 + h]));
      const float eg = 1.f / (1.f + __expf(-pr[552 + h]));
      gates[t * 8 + h] = make_float2(1.f - lg, lg * eg);
    }
  }
}

// ---------------------------------------------------------------------------
// Chunked scan.  gid bits: [b:1][chunk:4][h:3][d:7][n:4] -> 524288 threads.
// Step: mag=exp2(dv*Are2); (sn,co)=sincos_rev(dv*AimR); tr=h+betas*bxp;
//       h'=a*tr + gam*bx.
// COPY-FREE modulo-4 pipeline: 4 named stage sets; substep u loads the set
// consumed at substep u+2 (distance = 2 step-bodies, no rotation movs).
// Tail substeps prefetch up to 2 rows past each stream; all such addresses
// land inside later d_ws buffers (values unused) -- see workspace layout.
// part1 alpha-cumprod via S=sum(dv):  prod alpha = exp2(S*Are2)*cis(S*AimR);
// safe: mag underflows to 0 long before S*AimR leaves sincos range.
// ---------------------------------------------------------------------------
__global__ __launch_bounds__(256)
void scan_part1_k(const float2* __restrict__ dx, const float4* __restrict__ scanin,
                  const float2* __restrict__ gates, const float* __restrict__ A_log,
                  const float* __restrict__ A_imag, float4* __restrict__ csum) {
  const int gid = blockIdx.x * 256 + threadIdx.x;
  const int n  = gid & 15;
  const int d  = (gid >> 4) & 127;
  const int h  = (gid >> 11) & 7;
  const int ck = (gid >> 14) & 15;
  const int b  = gid >> 18;
  const int c  = h * 128 + d;

  const float Are2 = -__expf(A_log[h * 16 + n]) * 1.44269504f;  // *log2(e)
  const float AimR = A_imag[h * 16 + n] * 0.15915494f;          // /(2*pi)

  const int t0 = b * 1024 + ck * 64;
  float bxpr = 0.f, bxpi = 0.f;
  if (ck > 0) {
    const float xv = dx[(size_t)(t0 - 1) * 1024 + c].y;
    const float2 bp =
        reinterpret_cast<const float2*>(scanin)[2 * ((size_t)(t0 - 1) * 128 + h * 16 + n)];
    bxpr = xv * bp.x; bxpi = xv * bp.y;
  }

  const float2* dxp = dx + (size_t)t0 * 1024 + c;
  const float2* sp  = reinterpret_cast<const float2*>(scanin) +
                      2 * ((size_t)t0 * 128 + h * 16 + n);
  const float2* gp  = gates + (size_t)t0 * 8 + h;

  float2 dxv0, dxv1, dxv2, dxv3, bc0, bc1, bc2, bc3, bg0, bg1, bg2, bg3;
  // prologue: stage steps 0,1 into sets 0,1
  dxv0 = dxp[0];  dxv1 = dxp[1024];
  bc0  = sp[0];   bc1  = sp[256];
  bg0  = gp[0];   bg1  = gp[8];

  float S = 0.f, hr = 0.f, hi = 0.f;

#define P1_LOAD(j, so)                                                       \
  dxv##j = dxp[(so) * 1024]; bc##j = sp[(so) * 256]; bg##j = gp[(so) * 8];
#define P1_STEP(j)                                                           \
  {                                                                          \
    const float dv = dxv##j.x, xv = dxv##j.y;                                \
    const float betas = dv * bg##j.x;                                        \
    const float gam   = dv * bg##j.y;                                        \
    const float mag = fexp2(dv * Are2);                                      \
    const float rev = dv * AimR;                                             \
    const float sn = fsin_rev(rev), co = fcos_rev(rev);                      \
    const float are = mag * co, aim = mag * sn;                              \
    const float bxr = xv * bc##j.x, bxi = xv * bc##j.y;                      \
    const float tr = fmaf(betas, bxpr, hr);                                  \
    const float ti = fmaf(betas, bxpi, hi);                                  \
    hr = fmaf(are, tr, fmaf(-aim, ti, gam * bxr));                           \
    hi = fmaf(are, ti, fmaf(aim, tr, gam * bxi));                            \
    bxpr = bxr; bxpi = bxi;                                                  \
    S += dv;                                                                 \
  }

  for (int it = 0; it < 16; ++it) {
    P1_LOAD(2, 2) P1_STEP(0)
    P1_LOAD(3, 3) P1_STEP(1)
    P1_LOAD(0, 4) P1_STEP(2)
    P1_LOAD(1, 5) P1_STEP(3)
    dxp += 4096; sp += 1024; gp += 32;
  }
#undef P1_LOAD
#undef P1_STEP

  const float Amag = fexp2(S * Are2);
  const float Arev = S * AimR;
  csum[gid] = make_float4(Amag * fcos_rev(Arev), Amag * fsin_rev(Arev), hr, hi);
}

__global__ __launch_bounds__(256)
void scan_part2_k(const float4* __restrict__ csum, float2* __restrict__ hstart) {
  const int gid = blockIdx.x * 256 + threadIdx.x;  // 32768 total
  const int low = gid & 2047;
  const int h   = (gid >> 11) & 7;
  const int b   = gid >> 14;
  float hr = 0.f, hi = 0.f;
#pragma unroll
  for (int ck = 0; ck < 16; ++ck) {
    const int s = (((b * 16 + ck) * 8 + h) << 11) + low;
    hstart[s] = make_float2(hr, hi);
    const float4 cs = csum[s];
    const float nhr = cs.x * hr - cs.y * hi + cs.z;
    const float nhi = cs.x * hi + cs.y * hr + cs.w;
    hr = nhr; hi = nhi;
  }
}

__global__ __launch_bounds__(256)
void scan_part3_k(const float* __restrict__ gz, const float2* __restrict__ dx,
                  const float4* __restrict__ scanin, const float2* __restrict__ gates,
                  const float* __restrict__ A_log, const float* __restrict__ A_imag,
                  const float* __restrict__ D_param,
                  const float2* __restrict__ hstart, short* __restrict__ ygb) {
  const int gid = blockIdx.x * 256 + threadIdx.x;
  const int n  = gid & 15;
  const int d  = (gid >> 4) & 127;
  const int h  = (gid >> 11) & 7;
  const int ck = (gid >> 14) & 15;
  const int b  = gid >> 18;
  const int c  = h * 128 + d;

  const float Are2 = -__expf(A_log[h * 16 + n]) * 1.44269504f;
  const float AimR = A_imag[h * 16 + n] * 0.15915494f;
  const float Dc   = D_param[c];

  const int t0 = b * 1024 + ck * 64;
  float bxpr = 0.f, bxpi = 0.f;
  if (ck > 0) {
    const float xv = dx[(size_t)(t0 - 1) * 1024 + c].y;
    const float2 bp =
        reinterpret_cast<const float2*>(scanin)[2 * ((size_t)(t0 - 1) * 128 + h * 16 + n)];
    bxpr = xv * bp.x; bxpi = xv * bp.y;
  }
  const float2 h0 = hstart[gid];
  float hr = h0.x, hi = h0.y;

  const float2* dxp = dx + (size_t)t0 * 1024 + c;
  const float4* sp  = scanin + (size_t)t0 * 128 + h * 16 + n;
  const float2* gp  = gates + (size_t)t0 * 8 + h;
  const float*  zp  = gz + (size_t)t0 * 2048 + 1024 + c;  // pre-silu'd
  short*        yp  = ygb + (size_t)t0 * 1024 + c;

  float2 dxv0, dxv1, dxv2, dxv3, bg0, bg1, bg2, bg3;
  float4 bc0, bc1, bc2, bc3;
  float  zv0, zv1, zv2, zv3;
  // prologue: stage steps 0,1 into sets 0,1
  dxv0 = dxp[0];  dxv1 = dxp[1024];
  bc0  = sp[0];   bc1  = sp[128];
  bg0  = gp[0];   bg1  = gp[8];
  zv0  = zp[0];   zv1  = zp[2048];

#define P3_LOAD(j, so)                                                       \
  dxv##j = dxp[(so) * 1024]; bc##j = sp[(so) * 128]; bg##j = gp[(so) * 8];   \
  zv##j = zp[(so) * 2048];
#define P3_STEP(j, u)                                                        \
  {                                                                          \
    const float dv = dxv##j.x, xv = dxv##j.y;                                \
    const float betas = dv * bg##j.x;                                        \
    const float gam   = dv * bg##j.y;                                        \
    const float mag = fexp2(dv * Are2);                                      \
    const float rev = dv * AimR;                                             \
    const float sn = fsin_rev(rev), co = fcos_rev(rev);                      \
    const float are = mag * co, aim = mag * sn;                              \
    const float bxr = xv * bc##j.x, bxi = xv * bc##j.y;                      \
    const float tr = fmaf(betas, bxpr, hr);                                  \
    const float ti = fmaf(betas, bxpi, hi);                                  \
    hr = fmaf(are, tr, fmaf(-aim, ti, gam * bxr));                           \
    hi = fmaf(are, ti, fmaf(aim, tr, gam * bxi));                            \
    bxpr = bxr; bxpi = bxi;                                                  \
    float y = fmaf(hr, bc##j.z, hi * bc##j.w);                               \
    ROR_ADD(y, 0x121)                                                        \
    ROR_ADD(y, 0x122)                                                        \
    ROR_ADD(y, 0x124)                                                        \
    ROR_ADD(y, 0x128)                                                        \
    const short yo = f2bf(fmaf(Dc, xv, y) * zv##j);                          \
    if (n == 0) yp[(u) * 1024] = yo;                                         \
  }

  for (int it = 0; it < 16; ++it) {
    P3_LOAD(2, 2) P3_STEP(0, 0)
    P3_LOAD(3, 3) P3_STEP(1, 1)
    P3_LOAD(0, 4) P3_STEP(2, 2)
    P3_LOAD(1, 5) P3_STEP(3, 3)
    dxp += 4096; sp += 512; gp += 32; zp += 8192; yp += 4096;
  }
#undef P3_LOAD
#undef P3_STEP
}

// ---------------------------------------------------------------------------
extern "C" void kernel_launch(void* const* d_in, const int* in_sizes, int n_in,
                              void* d_out, int out_size, void* d_ws, size_t ws_size,
                              hipStream_t stream) {
  (void)in_sizes; (void)n_in; (void)out_size; (void)ws_size;
  const float* x       = (const float*)d_in[0];
  const float* W_in    = (const float*)d_in[1];
  const float* conv_w  = (const float*)d_in[2];
  const float* conv_b  = (const float*)d_in[3];
  const float* W_x     = (const float*)d_in[4];
  const float* W_dt    = (const float*)d_in[5];
  const float* b_dt    = (const float*)d_in[6];
  const float* A_log   = (const float*)d_in[7];
  const float* A_imag  = (const float*)d_in[8];
  const float* D_param = (const float*)d_in[9];
  const float* W_out   = (const float*)d_in[10];
  float* out = (float*)d_out;

  // workspace layout (float offsets); total 15,106,048 floats = 57.6 MiB.
  // Aliases (disjoint lifetimes): x_bf/win_bf/xc_bf live inside csum's slot
  // (all dead before part1 writes csum); wx_bf/wdtT inside hst's slot (dead
  // before part2 writes hst).  Scan pipeline prefetch overreads <=2 rows past
  // dx / scanin / gates / xz -- all land in subsequent ws buffers (allocated).
  float* ws = (float*)d_ws;
  float*  xz      = ws;                          // 4,194,304
  float*  proj    = ws + 4194304;                // 1,146,880
  float2* dx      = (float2*)(ws + 5341184);     // 4,194,304 (2M float2)
  float4* scanin  = (float4*)(ws + 9535488);     // 1,048,576
  float2* gates   = (float2*)(ws + 10584064);    //    65,536
  short*  yg_bf   = (short*)(ws + 10649600);     // 1,048,576 (2M shorts)
  short*  wout_bf = (short*)(ws + 11698176);     //   262,144
  float4* csum    = (float4*)(ws + 11960320);    // 2,097,152
  short*  x_bf    = (short*)(ws + 11960320);     //   [alias in csum]
  short*  win_bf  = (short*)(ws + 12484608);     //   [alias in csum]
  short*  xc_bf   = (short*)(ws + 13008896);     //   [alias in csum]
  float2* hst     = (float2*)(ws + 14057472);    // 1,048,576
  short*  wx_bf   = (short*)(ws + 14057472);     //   [alias in hst]
  float*  wdtT    = ws + 14344192;               //   [alias in hst]

  // 0) conversions + W_dt transpose (one kernel)
  cvt_all_k<<<dim3(3248), dim3(256), 0, stream>>>(x, W_in, W_x, W_out, W_dt,
                                                  x_bf, win_bf, wx_bf, wout_bf,
                                                  wdtT);
  // 1) xz = x @ W_in^T        (M=2048, N=2048, K=512)
  gemm_bf16_128<<<dim3(16, 16), dim3(256), 0, stream>>>(x_bf, win_bf, xz, 2048, 512);
  // 2) dx.y = silu(dwconv(x_proj)) (+ bf16 copy); in-place silu on z half
  conv_silu_k<<<dim3(8192), dim3(256), 0, stream>>>(xz, conv_w, conv_b,
                                                    (float*)dx, xc_bf);
  // 3) proj = xc @ W_x^T      (M=2048, N=560, K=1024)
  gemm_bf16_64<<<dim3(9, 32), dim3(256), 0, stream>>>(xc_bf, wx_bf, proj, 560, 1024);
  // 4) dx.x = delta; scanin/gates pack
  pack2_k<<<dim3(9216), dim3(256), 0, stream>>>(proj, wdtT, b_dt, (float*)dx,
                                                scanin, gates);
  // 5) chunked scan (copy-free modulo-4 pipeline)
  scan_part1_k<<<dim3(2048), dim3(256), 0, stream>>>(dx, scanin, gates, A_log,
                                                     A_imag, csum);
  scan_part2_k<<<dim3(128), dim3(256), 0, stream>>>(csum, hst);
  scan_part3_k<<<dim3(2048), dim3(256), 0, stream>>>(xz, dx, scanin, gates, A_log,
                                                     A_imag, D_param, hst, yg_bf);
  // 6) out = yg_bf @ W_out^T  (M=2048, N=512, K=1024)
  gemm_bf16_64<<<dim3(8, 32), dim3(256), 0, stream>>>(yg_bf, wout_bf, out, 512, 1024);
}